// Round 15
// baseline (1024.307 us; speedup 1.0000x reference)
//
#include <hip/hip_runtime.h>

#define LOG20F 2.9957322735539909f
#define AS1 __attribute__((address_space(1)))
#define AS3 __attribute__((address_space(3)))

typedef __attribute__((ext_vector_type(4))) short short4v;
typedef __attribute__((ext_vector_type(8))) short short8;
typedef __attribute__((ext_vector_type(8))) __bf16 bf16x8;
typedef __attribute__((ext_vector_type(4))) float f32x4;

__device__ __forceinline__ short f2bf(float f) {
  unsigned u = __float_as_uint(f);
  u = u + 0x7fffu + ((u >> 16) & 1u);   // RNE
  return (short)(u >> 16);
}
__device__ __forceinline__ float bf2f(short s) {
  return __uint_as_float(((unsigned)(unsigned short)s) << 16);
}

// T1: bijective XCD-aware remap + 4x4 supertile ordering within each XCD
// chunk (measured r8: energy FETCH 147->98 MB). Fallback when not /4.
__device__ __forceinline__ void xcd_map(int& bx, int& by, int& bz) {
  int gx = gridDim.x, gy = gridDim.y;
  int nwg = gx * gy * (int)gridDim.z;
  int lin = bx + gx * (by + gy * bz);
  int q = nwg >> 3, r = nwg & 7;
  int xcd = lin & 7, idx = lin >> 3;
  int wg = (xcd < r ? xcd * (q + 1) : r * (q + 1) + (xcd - r) * q) + idx;
  int per_z = gx * gy;
  bz = wg / per_z;
  int rz = wg - bz * per_z;
  if ((gx & 3) == 0 && (gy & 3) == 0) {
    int nstx = gx >> 2;
    int st = rz >> 4, w = rz & 15;
    bx = ((st % nstx) << 2) + (w & 3);
    by = ((st / nstx) << 2) + (w >> 2);
  } else {
    bx = rz % gx;
    by = rz / gx;
  }
}

// ===========================================================================
// 8-phase 256x256 BT GEMM (r8-proven schedule, BK=64, 8 waves 2Mx4N).
// r14 change: stage* issued FIRST in each phase (T3 recipe — HBM latency
// starts one ds_read-cluster earlier). Pure within-phase reorder; barrier
// structure and vmcnt ledger unchanged (ds_reads don't count in vmcnt).
// EPI: 0 scale-only, 1 PV (acc*scale/rs[row] + add), 2 energy (exp + rsum).
// EPI 0/1 use dead-LDS staged coalesced stores (r13 win); EPI 2 direct (r14).
// ===========================================================================
template <int EPI>
__global__ __launch_bounds__(512, 2) void gemm8(
    const short* __restrict__ A, const short* __restrict__ B,
    short* __restrict__ C, const short* __restrict__ addp,
    float* __restrict__ rs,
    int K, int lda, int ldb, int ldc, int ldadd,
    long abatch, long bbatch, long cbatch, long addbatch, float scale)
{
  __shared__ __align__(16) short lsmem[4][256 * 64];   // lA=0,1  lB=2,3
  __shared__ float rsum_l[256];
#define LA(b) (lsmem[(b)])
#define LB(b) (lsmem[2 + (b)])

  int bx = blockIdx.x, by = blockIdx.y, bz = blockIdx.z;
  xcd_map(bx, by, bz);

  const int tid = threadIdx.x;           // 0..511
  const int lane = tid & 63, wid = tid >> 6;
  const int wr = wid >> 2, wc = wid & 3; // wave tile: rows wr*128, cols wc*64

  const long bm = (long)bx * 256, bn = (long)by * 256;
  const short* Ab = A + (long)bz * abatch + bm * lda;
  const short* Bb = B + (long)bz * bbatch + bn * ldb;

  f32x4 acc[8][4] = {};

  const int NKT = K >> 6;   // K-tiles of 64 (even for all call sites)

  // stage one half-tile (16KB, 2 x gload_lds/thread). half: 0=rows0-127.
  auto stageA = [&](int buf, int kt, int half) {
    int k0 = kt << 6;
#pragma unroll
    for (int i = 0; i < 2; ++i) {
      int idx = i * 512 + tid;
      int rl = idx >> 3, ch = idx & 7;
      int row = half * 128 + rl;
      int chs = ch ^ (row & 7);
      __builtin_amdgcn_global_load_lds(
          (const AS1 void*)(Ab + (long)row * lda + k0 + chs * 8),
          (AS3 void*)(&LA(buf)[row * 64 + ch * 8]), 16, 0, 0);
    }
  };
  auto stageB = [&](int buf, int kt, int half) {
    int k0 = kt << 6;
#pragma unroll
    for (int i = 0; i < 2; ++i) {
      int idx = i * 512 + tid;
      int rl = idx >> 3, ch = idx & 7;
      int row = half * 128 + rl;
      int chs = ch ^ (row & 7);
      __builtin_amdgcn_global_load_lds(
          (const AS1 void*)(Bb + (long)row * ldb + k0 + chs * 8),
          (AS3 void*)(&LB(buf)[row * 64 + ch * 8]), 16, 0, 0);
    }
  };

  const int rr = lane & 15, cl = lane >> 4;
  bf16x8 bfr[4][2], af[2][2];

  // fragment loads (ds_read_b128); q = row quadrant 0..3 of the wave tile
  auto loadA = [&](int buf, int q) {
#pragma unroll
    for (int f = 0; f < 2; ++f) {
      int row = wr * 128 + q * 32 + f * 16 + rr;
#pragma unroll
      for (int kk = 0; kk < 2; ++kk) {
        int pch = (kk * 4 + cl) ^ (row & 7);
        af[f][kk] = *(const bf16x8*)&LA(buf)[row * 64 + pch * 8];
      }
    }
  };
  auto loadB = [&](int buf) {
#pragma unroll
    for (int ni = 0; ni < 4; ++ni) {
      int row = wc * 64 + ni * 16 + rr;
#pragma unroll
      for (int kk = 0; kk < 2; ++kk) {
        int pch = (kk * 4 + cl) ^ (row & 7);
        bfr[ni][kk] = *(const bf16x8*)&LB(buf)[row * 64 + pch * 8];
      }
    }
  };

#define BAR() __builtin_amdgcn_s_barrier()
#define LGKM0() asm volatile("s_waitcnt lgkmcnt(0)" ::: "memory")
#define MFMA_Q(q)                                                        \
  do {                                                                   \
    __builtin_amdgcn_s_setprio(1);                                       \
    _Pragma("unroll")                                                    \
    for (int f = 0; f < 2; ++f)                                          \
      _Pragma("unroll")                                                  \
      for (int ni = 0; ni < 4; ++ni)                                     \
        _Pragma("unroll")                                                \
        for (int kk = 0; kk < 2; ++kk)                                   \
          acc[(q) * 2 + f][ni] = __builtin_amdgcn_mfma_f32_16x16x32_bf16(\
              af[f][kk], bfr[ni][kk], acc[(q) * 2 + f][ni], 0, 0, 0);    \
    __builtin_amdgcn_s_setprio(0);                                       \
  } while (0)

  // prologue: tile0 (buf0) fully + tile1 B-halves (buf1) = 12 loads/thread
  stageB(0, 0, 0); stageB(0, 0, 1);
  stageA(0, 0, 0); stageA(0, 0, 1);
  stageB(1, 1, 0); stageB(1, 1, 1);
  asm volatile("s_waitcnt vmcnt(4)" ::: "memory");   // tile0 landed
  BAR();

  for (int t2 = 0; t2 < NKT; t2 += 2) {
    const bool more = (t2 + 4 <= NKT);   // tiles t2+2 / t2+3 exist
    // ---- K-tile t2 (buf0) ----  (stage issued before ds_reads, T3)
    stageA(1, t2 + 1, 0); stageA(1, t2 + 1, 1);
    loadB(0); loadA(0, 0);
    BAR(); LGKM0(); MFMA_Q(0); BAR();
    if (more) stageB(0, t2 + 2, 0);
    loadA(0, 1);
    BAR(); LGKM0(); MFMA_Q(1); BAR();
    if (more) stageB(0, t2 + 2, 1);
    loadA(0, 2);
    BAR(); LGKM0(); MFMA_Q(2); BAR();
    loadA(0, 3);
    if (more) { asm volatile("s_waitcnt vmcnt(4)" ::: "memory"); }
    else      { asm volatile("s_waitcnt vmcnt(0)" ::: "memory"); }
    BAR(); LGKM0(); MFMA_Q(3); BAR();
    // ---- K-tile t2+1 (buf1) ----
    if (more) stageA(0, t2 + 2, 0);
    loadB(1); loadA(1, 0);
    BAR(); LGKM0(); MFMA_Q(0); BAR();
    if (more) stageA(0, t2 + 2, 1);
    loadA(1, 1);
    BAR(); LGKM0(); MFMA_Q(1); BAR();
    if (more) stageB(1, t2 + 3, 0);
    loadA(1, 2);
    BAR(); LGKM0(); MFMA_Q(2); BAR();
    if (more) stageB(1, t2 + 3, 1);
    loadA(1, 3);
    if (more) { asm volatile("s_waitcnt vmcnt(4)" ::: "memory"); }
    else      { asm volatile("s_waitcnt vmcnt(0)" ::: "memory"); }
    BAR(); LGKM0(); MFMA_Q(3); BAR();
  }
#undef BAR
#undef LGKM0
#undef MFMA_Q

  // ---- epilogue: D lane map col=lane&15, row=(lane>>4)*4+r (m89/m91) ----
  if constexpr (EPI == 2) {
    // energy: direct stores (r11 form; measured faster than LDS staging)
    if (tid < 256) rsum_l[tid] = 0.f;
    __syncthreads();
#pragma unroll
    for (int mi = 0; mi < 8; ++mi) {
      int lrow0 = wr * 128 + (mi >> 1) * 32 + (mi & 1) * 16 + (cl << 2);
#pragma unroll
      for (int r = 0; r < 4; ++r) {
        float part = 0.f;
#pragma unroll
        for (int ni = 0; ni < 4; ++ni) {
          long col = bn + wc * 64 + ni * 16 + rr;
          float e = __expf(acc[mi][ni][r] * scale);
          C[(long)bz * cbatch + (bm + lrow0 + r) * ldc + col] = f2bf(e);
          part += e;
        }
        part += __shfl_xor(part, 1);
        part += __shfl_xor(part, 2);
        part += __shfl_xor(part, 4);
        part += __shfl_xor(part, 8);
        if (rr == 0) atomicAdd(&rsum_l[lrow0 + r], part);
      }
    }
    __syncthreads();
    if (tid < 256) atomicAdd(&rs[(long)bz * 4096 + bm + tid], rsum_l[tid]);
  } else {
    // EPI 0/1: stage result in dead operand LDS, then coalesced short8 stores
    short* cstage = &lsmem[0][0];
    auto stc = [&](int row, int col, short v) {
      int g = (col >> 3) ^ ((row >> 2) & 7);
      cstage[row * 256 + g * 8 + (col & 7)] = v;
    };
    if constexpr (EPI == 1) {
#pragma unroll
      for (int mi = 0; mi < 8; ++mi) {
        int lrow0 = wr * 128 + (mi >> 1) * 32 + (mi & 1) * 16 + (cl << 2);
        float inv[4];
#pragma unroll
        for (int r = 0; r < 4; ++r)
          inv[r] = 1.f / rs[(long)bz * 4096 + bm + lrow0 + r];
#pragma unroll
        for (int ni = 0; ni < 4; ++ni) {
          int col = wc * 64 + ni * 16 + rr;
#pragma unroll
          for (int r = 0; r < 4; ++r)
            stc(lrow0 + r, col, f2bf(acc[mi][ni][r] * scale * inv[r]));
        }
      }
    } else {
#pragma unroll
      for (int mi = 0; mi < 8; ++mi) {
        int lrow0 = wr * 128 + (mi >> 1) * 32 + (mi & 1) * 16 + (cl << 2);
#pragma unroll
        for (int ni = 0; ni < 4; ++ni) {
          int col = wc * 64 + ni * 16 + rr;
#pragma unroll
          for (int r = 0; r < 4; ++r)
            stc(lrow0 + r, col, f2bf(acc[mi][ni][r] * scale));
        }
      }
    }
    __syncthreads();
    // coalesced store: 16 x short8 per thread (skip-add fused for EPI=1)
#pragma unroll
    for (int it = 0; it < 16; ++it) {
      int g = it * 512 + tid;            // granule id 0..8191
      int row = g >> 5, cg = g & 31;
      int gphys = cg ^ ((row >> 2) & 7);
      short8 v8 = *(short8*)&cstage[row * 256 + gphys * 8];
      if constexpr (EPI == 1) {
        const short8 a8 = *(const short8*)&addp[
            (long)bz * addbatch + (bm + row) * (long)ldadd + bn + cg * 8];
#pragma unroll
        for (int j = 0; j < 8; ++j) v8[j] = f2bf(bf2f(v8[j]) + bf2f(a8[j]));
      }
      *(short8*)&C[(long)bz * cbatch + (bm + row) * (long)ldc + bn + cg * 8] = v8;
    }
  }
#undef LA
#undef LB
}

// ---------------------------------------------------------------------------
// 2-phase 128-tile BT GEMM (round-4 proven) for the small c1/c2 GEMMs.
// ---------------------------------------------------------------------------
__device__ __forceinline__ int swz32(int row, int ch) {
  return row * 32 + ((ch ^ ((row >> 1) & 3)) << 3);
}

template <int BM, int BN, int WR, int WC, int EPI>
__global__ __launch_bounds__(WR * WC * 64, 4) void gemm_bt(
    const short* __restrict__ A, const short* __restrict__ B,
    short* __restrict__ C, const short* __restrict__ addp,
    const float* __restrict__ sc, const float* __restrict__ sh,
    int K, int lda, int ldb, int ldc,
    long abatch, long bbatch, long cbatch, float scale)
{
  constexpr int NTH = WR * WC * 64;
  constexpr int WM = BM / WR, WN = BN / WC;
  constexpr int MR = WM / 16, NR = WN / 16;
  constexpr int CA = (BM * 4) / NTH, CB = (BN * 4) / NTH;

  __shared__ __align__(16) short lA[2][BM * 32];
  __shared__ __align__(16) short lB[2][BN * 32];

  int bx = blockIdx.x, by = blockIdx.y, bz = blockIdx.z;
  xcd_map(bx, by, bz);

  const int tid = threadIdx.x;
  const int lane = tid & 63, wid = tid >> 6;
  const int wr = wid / WC, wc = wid % WC;

  const long bm = (long)bx * BM, bn = (long)by * BN;
  const short* Ab = A + (long)bz * abatch + bm * lda;
  const short* Bb = B + (long)bz * bbatch + bn * ldb;

  f32x4 acc[MR][NR] = {};

  auto stage = [&](int buf, int k0) {
#pragma unroll
    for (int i = 0; i < CA; ++i) {
      int idx = i * NTH + tid, row = idx >> 2, ch = idx & 3;
      int chs = ch ^ ((row >> 1) & 3);
      __builtin_amdgcn_global_load_lds(
          (const AS1 void*)(Ab + (long)row * lda + k0 + chs * 8),
          (AS3 void*)(&lA[buf][idx * 8]), 16, 0, 0);
    }
#pragma unroll
    for (int i = 0; i < CB; ++i) {
      int idx = i * NTH + tid, row = idx >> 2, ch = idx & 3;
      int chs = ch ^ ((row >> 1) & 3);
      __builtin_amdgcn_global_load_lds(
          (const AS1 void*)(Bb + (long)row * ldb + k0 + chs * 8),
          (AS3 void*)(&lB[buf][idx * 8]), 16, 0, 0);
    }
  };

  const int NT = K >> 5;
  stage(0, 0);
  __syncthreads();
  int cur = 0;
  for (int t = 0; t < NT; ++t) {
    if (t + 1 < NT) stage(cur ^ 1, (t + 1) << 5);
    const int ch = lane >> 4, rrow = lane & 15;
    bf16x8 af[MR], bfr[NR];
#pragma unroll
    for (int mi = 0; mi < MR; ++mi) {
      int row = wr * WM + mi * 16 + rrow;
      af[mi] = *(const bf16x8*)&lA[cur][swz32(row, ch)];
    }
#pragma unroll
    for (int ni = 0; ni < NR; ++ni) {
      int row = wc * WN + ni * 16 + rrow;
      bfr[ni] = *(const bf16x8*)&lB[cur][swz32(row, ch)];
    }
    __builtin_amdgcn_s_setprio(1);
#pragma unroll
    for (int mi = 0; mi < MR; ++mi)
#pragma unroll
      for (int ni = 0; ni < NR; ++ni)
        acc[mi][ni] = __builtin_amdgcn_mfma_f32_16x16x32_bf16(
            af[mi], bfr[ni], acc[mi][ni], 0, 0, 0);
    __builtin_amdgcn_s_setprio(0);
    __syncthreads();
    cur ^= 1;
  }

#pragma unroll
  for (int mi = 0; mi < MR; ++mi) {
    long row0 = bm + wr * WM + mi * 16 + ((lane >> 4) << 2);
#pragma unroll
    for (int ni = 0; ni < NR; ++ni) {
      long col = bn + wc * WN + ni * 16 + (lane & 15);
#pragma unroll
      for (int r = 0; r < 4; ++r) {
        long off = (long)bz * cbatch + (row0 + r) * ldc + col;
        float v = acc[mi][ni][r] * scale;
        if constexpr (EPI == 1) v += bf2f(addp[off]);
        if constexpr (EPI == 2) {
          float y = v * sc[col] + sh[col];
          v = y / (1.f + __expf(-y));
        }
        C[off] = f2bf(v);
      }
    }
  }
}

// ---------------------------------------------------------------------------
__global__ __launch_bounds__(256) void transpose_cvt(
    const float* __restrict__ in, short* __restrict__ out, int C, int N)
{
  __shared__ float tile[32][33];
  int n0 = blockIdx.x * 32, c0 = blockIdx.y * 32;
  long z = (long)blockIdx.z * C * N;
  int tx = threadIdx.x & 31, ty = threadIdx.x >> 5;
#pragma unroll
  for (int r = 0; r < 4; ++r) {
    int cc = ty + r * 8;
    tile[cc][tx] = in[z + (long)(c0 + cc) * N + n0 + tx];
  }
  __syncthreads();
#pragma unroll
  for (int r = 0; r < 4; ++r) {
    int nn = ty + r * 8;
    out[z + (long)(n0 + nn) * C + c0 + tx] = f2bf(tile[tx][nn]);
  }
}

__global__ __launch_bounds__(256) void cvt_bf16(
    const float* __restrict__ in, short* __restrict__ out, long n)
{
  long i = ((long)blockIdx.x * 256 + threadIdx.x) * 4;
  if (i >= n) return;
  const float* p = in + i;
  short4v s;
  s[0] = f2bf(p[0]); s[1] = f2bf(p[1]); s[2] = f2bf(p[2]); s[3] = f2bf(p[3]);
  *(short4v*)(out + i) = s;
}

__global__ void bn_prep(const float* g1, const float* b1, const float* m1, const float* v1,
                        const float* g2, const float* b2, const float* m2, const float* v2,
                        float* s1, float* t1, float* s2, float* t2)
{
  int i = threadIdx.x;
  if (i < 256) { float s = g1[i] * rsqrtf(v1[i] + 1e-5f); s1[i] = s; t1[i] = b1[i] - m1[i] * s; }
  if (i < 64)  { float s = g2[i] * rsqrtf(v2[i] + 1e-5f); s2[i] = s; t2[i] = b2[i] - m2[i] * s; }
}

__global__ __launch_bounds__(256) void zerof(float* __restrict__ p, int n)
{
  int i = blockIdx.x * 256 + threadIdx.x;
  if (i < n) p[i] = 0.f;
}

__global__ __launch_bounds__(256) void c3_out(
    const short* __restrict__ y2, const float* __restrict__ w,
    const float* __restrict__ bias, float* __restrict__ o, int total)
{
  int i = blockIdx.x * 256 + threadIdx.x;
  if (i >= total) return;
  const short8* r = (const short8*)(y2 + (long)i * 64);
  float acc = 0.f;
#pragma unroll
  for (int j0 = 0; j0 < 8; ++j0) {
    short8 v = r[j0];
#pragma unroll
    for (int j = 0; j < 8; ++j) acc += bf2f(v[j]) * w[j0 * 8 + j];
  }
  acc += bias[0];
  float x = acc * LOG20F;
  o[i] = 1.f / (1.f + __expf(-x));
}

// ---------------------------------------------------------------------------
extern "C" void kernel_launch(void* const* d_in, const int* in_sizes, int n_in,
                              void* d_out, int out_size, void* d_ws, size_t ws_size,
                              hipStream_t stream) {
  const float* pcd  = (const float*)d_in[0];
  const float* img  = (const float*)d_in[1];
  const float* qw   = (const float*)d_in[2];
  const float* kw   = (const float*)d_in[3];
  const float* vw   = (const float*)d_in[4];
  const float* skw  = (const float*)d_in[5];
  const float* c1w  = (const float*)d_in[6];
  const float* bn1g = (const float*)d_in[7];
  const float* bn1b = (const float*)d_in[8];
  const float* bn1m = (const float*)d_in[9];
  const float* bn1v = (const float*)d_in[10];
  const float* c2w  = (const float*)d_in[11];
  const float* bn2g = (const float*)d_in[12];
  const float* bn2b = (const float*)d_in[13];
  const float* bn2m = (const float*)d_in[14];
  const float* bn2v = (const float*)d_in[15];
  const float* c3w  = (const float*)d_in[16];
  const float* c3b  = (const float*)d_in[17];
  float* out = (float*)d_out;

  char* ws = (char*)d_ws;
  const long QS  = 4096L * 1024;   // (4096,1024) elems
  const long QS2 = 4096L * 2048;   // fused q|skip
  const long ES  = 4096L * 4096;
  const size_t ALGN = 256;
  auto align_up = [&](size_t x) { return (x + ALGN - 1) & ~(ALGN - 1); };

  size_t oPcd  = 0;
  size_t oImg  = align_up(oPcd + 8L * 4096 * 1152 * 2);
  size_t oQsk  = align_up(oImg + 8L * 4096 * 1024 * 2);
  size_t oKt   = align_up(oQsk + 8L * QS2 * 2);
  size_t oV    = align_up(oKt  + 8L * QS * 2);
  size_t oWqs  = align_up(oV   + 8L * QS * 2);
  size_t oWk   = align_up(oWqs + 2048L * 1152 * 2);
  size_t oWv   = align_up(oWk + 1024L * 1024 * 2);
  size_t oC1   = align_up(oWv + 1024L * 1024 * 2);
  size_t oC2   = align_up(oC1 + 256L * 1024 * 2);
  size_t oS1   = align_up(oC2 + 64L * 256 * 2);
  size_t oT1   = align_up(oS1 + 256 * 4);
  size_t oS2   = align_up(oT1 + 256 * 4);
  size_t oT2   = align_up(oS2 + 64 * 4);
  size_t oRs   = align_up(oT2 + 64 * 4);
  size_t oEnd  = align_up(oRs + 8L * 4096 * 4);

  short* pcdT  = (short*)(ws + oPcd);
  short* imgT  = (short*)(ws + oImg);
  short* qsk   = (short*)(ws + oQsk);   // [b][4096][2048]: q 0-1023, skip 1024+
  short* kt    = (short*)(ws + oKt);
  short* vbuf  = (short*)(ws + oV);
  short* wqsk  = (short*)(ws + oWqs);   // [2048][1152]: Wq rows then Wskip rows
  short* wkb   = (short*)(ws + oWk);
  short* wvb   = (short*)(ws + oWv);
  short* c1b   = (short*)(ws + oC1);
  short* c2b   = (short*)(ws + oC2);
  float* s1 = (float*)(ws + oS1); float* t1 = (float*)(ws + oT1);
  float* s2 = (float*)(ws + oS2); float* t2 = (float*)(ws + oT2);
  float* rsum = (float*)(ws + oRs);

  // attn/xt: NB=8 -> fresh 256MB attn + 64MB xt after oEnd; NB=4 -> attn
  // aliases region A [pcdT|imgT] (128 <= 142.6 MB), xt fresh; NB=2 ->
  // attn + xt both inside region A.
  int NB; short *attn, *xt;
  if (ws_size >= oEnd + (size_t)(8L * ES * 2) + (size_t)(8L * QS * 2)) {
    NB = 8; attn = (short*)(ws + oEnd);
    xt = (short*)(ws + align_up(oEnd + (size_t)(8L * ES * 2)));
  } else if (ws_size >= oEnd + (size_t)(8L * QS * 2)) {
    NB = 4; attn = (short*)(ws + 0); xt = (short*)(ws + oEnd);
  } else {
    NB = 2; attn = (short*)(ws + 0);
    xt = (short*)(ws + align_up((size_t)(2L * ES * 2)));
  }
  short* y1t = qsk;   // qsk dead after attention loop
  short* y2t = kt;    // kt dead after attention loop

  // weight converts + bn prep
  cvt_bf16<<<dim3(1152), 256, 0, stream>>>(qw,  wqsk,                1024L * 1152);
  cvt_bf16<<<dim3(1152), 256, 0, stream>>>(skw, wqsk + 1024L * 1152, 1024L * 1152);
  cvt_bf16<<<dim3(1024), 256, 0, stream>>>(kw,  wkb,  1024L * 1024);
  cvt_bf16<<<dim3(1024), 256, 0, stream>>>(vw,  wvb,  1024L * 1024);
  cvt_bf16<<<dim3(256),  256, 0, stream>>>(c1w, c1b,  256L * 1024);
  cvt_bf16<<<dim3(16),   256, 0, stream>>>(c2w, c2b,  64L * 256);
  bn_prep<<<1, 256, 0, stream>>>(bn1g, bn1b, bn1m, bn1v, bn2g, bn2b, bn2m, bn2v,
                                 s1, t1, s2, t2);
  zerof<<<dim3(128), 256, 0, stream>>>(rsum, 8 * 4096);
  transpose_cvt<<<dim3(128, 36, 8), 256, 0, stream>>>(pcd, pcdT, 1152, 4096);
  transpose_cvt<<<dim3(128, 32, 8), 256, 0, stream>>>(img, imgT, 1024, 4096);

  // fused q+skip projection: qsk[n, 0:2048], K=1152 (NKT=18)
  gemm8<0><<<dim3(16, 8, 8), 512, 0, stream>>>(
      pcdT, wqsk, qsk, nullptr, nullptr,
      1152, 1152, 1152, 2048, 0, 4096L * 1152, 0, QS2, 0, 1.f);
  // kt projection
  gemm8<0><<<dim3(16, 4, 8), 512, 0, stream>>>(
      imgT, wkb, kt, nullptr, nullptr,
      1024, 1024, 1024, 1024, 0, QS, 0, QS, 0, 1.f);
  // v projection (transposed output): v[o, m]
  gemm8<0><<<dim3(4, 16, 8), 512, 0, stream>>>(
      wvb, imgT, vbuf, nullptr, nullptr,
      1024, 1024, 1024, 4096, 0, 0, QS, QS, 0, 1.f);

  // attention (softmax folded into GEMM epilogues via rsum)
  for (int b0 = 0; b0 < 8; b0 += NB) {
    // e[n,m] = exp(E[n,m]/32); rsum[n] += row sums
    gemm8<2><<<dim3(16, 16, NB), 512, 0, stream>>>(
        qsk + (long)b0 * QS2, kt + (long)b0 * QS, attn, nullptr,
        rsum + (long)b0 * 4096,
        1024, 2048, 1024, 4096, 0, QS2, QS, ES, 0, 0.03125f);
    // xt[n,c] = (sum_m e[n,m] v[c,m]) / rsum[n] + skip[n,c]
    gemm8<1><<<dim3(16, 4, NB), 512, 0, stream>>>(
        attn, vbuf + (long)b0 * QS, xt + (long)b0 * QS,
        qsk + (long)b0 * QS2 + 1024, rsum + (long)b0 * 4096,
        4096, 4096, 4096, 1024, 2048, ES, QS, QS, QS2, 1.f);
  }

  // c1/c2: proven 2-phase 128-tile path
  gemm_bt<128, 128, 2, 2, 2><<<dim3(32, 2, 8), 256, 0, stream>>>(
      xt, c1b, y1t, nullptr, s1, t1,
      1024, 1024, 1024, 256, QS, 0, 4096L * 256, 1.f);
  gemm_bt<128, 64, 4, 1, 2><<<dim3(32, 1, 8), 256, 0, stream>>>(
      y1t, c2b, y2t, nullptr, s2, t2,
      256, 256, 256, 64, 4096L * 256, 0, 4096L * 64, 1.f);
  c3_out<<<dim3(128), 256, 0, stream>>>(y2t, c3w, c3b, out, 32768);

  (void)in_sizes; (void)n_in; (void)out_size; (void)ws_size;
}

// Round 16
// 1000.521 us; speedup vs baseline: 1.0238x; 1.0238x over previous
//
#include <hip/hip_runtime.h>

#define LOG20F 2.9957322735539909f
#define AS1 __attribute__((address_space(1)))
#define AS3 __attribute__((address_space(3)))

typedef __attribute__((ext_vector_type(4))) short short4v;
typedef __attribute__((ext_vector_type(8))) short short8;
typedef __attribute__((ext_vector_type(8))) __bf16 bf16x8;
typedef __attribute__((ext_vector_type(4))) float f32x4;

__device__ __forceinline__ short f2bf(float f) {
  unsigned u = __float_as_uint(f);
  u = u + 0x7fffu + ((u >> 16) & 1u);   // RNE
  return (short)(u >> 16);
}
__device__ __forceinline__ float bf2f(short s) {
  return __uint_as_float(((unsigned)(unsigned short)s) << 16);
}

// T1: bijective XCD-aware remap + 4x4 supertile ordering within each XCD
// chunk (measured r8: energy FETCH 147->98 MB). Fallback when not /4.
__device__ __forceinline__ void xcd_map(int& bx, int& by, int& bz) {
  int gx = gridDim.x, gy = gridDim.y;
  int nwg = gx * gy * (int)gridDim.z;
  int lin = bx + gx * (by + gy * bz);
  int q = nwg >> 3, r = nwg & 7;
  int xcd = lin & 7, idx = lin >> 3;
  int wg = (xcd < r ? xcd * (q + 1) : r * (q + 1) + (xcd - r) * q) + idx;
  int per_z = gx * gy;
  bz = wg / per_z;
  int rz = wg - bz * per_z;
  if ((gx & 3) == 0 && (gy & 3) == 0) {
    int nstx = gx >> 2;
    int st = rz >> 4, w = rz & 15;
    bx = ((st % nstx) << 2) + (w & 3);
    by = ((st / nstx) << 2) + (w >> 2);
  } else {
    bx = rz % gx;
    by = rz / gx;
  }
}

// ===========================================================================
// 8-phase 256x256 BT GEMM (r8-proven schedule, BK=64, 8 waves 2Mx4N).
// r15 A/B closed: ds_reads-first (this form) beats stage-first by ~10%.
// EPI: 0 scale-only, 1 PV (acc*scale/rs[row] + add), 2 energy (exp + rsum).
// EPI 0/1 use dead-LDS staged coalesced stores (r13 win); EPI 2 direct (r14).
// ===========================================================================
template <int EPI>
__global__ __launch_bounds__(512, 2) void gemm8(
    const short* __restrict__ A, const short* __restrict__ B,
    short* __restrict__ C, const short* __restrict__ addp,
    float* __restrict__ rs,
    int K, int lda, int ldb, int ldc, int ldadd,
    long abatch, long bbatch, long cbatch, long addbatch, float scale)
{
  __shared__ __align__(16) short lsmem[4][256 * 64];   // lA=0,1  lB=2,3
  __shared__ float rsum_l[256];
#define LA(b) (lsmem[(b)])
#define LB(b) (lsmem[2 + (b)])

  int bx = blockIdx.x, by = blockIdx.y, bz = blockIdx.z;
  xcd_map(bx, by, bz);

  const int tid = threadIdx.x;           // 0..511
  const int lane = tid & 63, wid = tid >> 6;
  const int wr = wid >> 2, wc = wid & 3; // wave tile: rows wr*128, cols wc*64

  const long bm = (long)bx * 256, bn = (long)by * 256;
  const short* Ab = A + (long)bz * abatch + bm * lda;
  const short* Bb = B + (long)bz * bbatch + bn * ldb;

  f32x4 acc[8][4] = {};

  const int NKT = K >> 6;   // K-tiles of 64 (even for all call sites)

  // stage one half-tile (16KB, 2 x gload_lds/thread). half: 0=rows0-127.
  auto stageA = [&](int buf, int kt, int half) {
    int k0 = kt << 6;
#pragma unroll
    for (int i = 0; i < 2; ++i) {
      int idx = i * 512 + tid;
      int rl = idx >> 3, ch = idx & 7;
      int row = half * 128 + rl;
      int chs = ch ^ (row & 7);
      __builtin_amdgcn_global_load_lds(
          (const AS1 void*)(Ab + (long)row * lda + k0 + chs * 8),
          (AS3 void*)(&LA(buf)[row * 64 + ch * 8]), 16, 0, 0);
    }
  };
  auto stageB = [&](int buf, int kt, int half) {
    int k0 = kt << 6;
#pragma unroll
    for (int i = 0; i < 2; ++i) {
      int idx = i * 512 + tid;
      int rl = idx >> 3, ch = idx & 7;
      int row = half * 128 + rl;
      int chs = ch ^ (row & 7);
      __builtin_amdgcn_global_load_lds(
          (const AS1 void*)(Bb + (long)row * ldb + k0 + chs * 8),
          (AS3 void*)(&LB(buf)[row * 64 + ch * 8]), 16, 0, 0);
    }
  };

  const int rr = lane & 15, cl = lane >> 4;
  bf16x8 bfr[4][2], af[2][2];

  // fragment loads (ds_read_b128); q = row quadrant 0..3 of the wave tile
  auto loadA = [&](int buf, int q) {
#pragma unroll
    for (int f = 0; f < 2; ++f) {
      int row = wr * 128 + q * 32 + f * 16 + rr;
#pragma unroll
      for (int kk = 0; kk < 2; ++kk) {
        int pch = (kk * 4 + cl) ^ (row & 7);
        af[f][kk] = *(const bf16x8*)&LA(buf)[row * 64 + pch * 8];
      }
    }
  };
  auto loadB = [&](int buf) {
#pragma unroll
    for (int ni = 0; ni < 4; ++ni) {
      int row = wc * 64 + ni * 16 + rr;
#pragma unroll
      for (int kk = 0; kk < 2; ++kk) {
        int pch = (kk * 4 + cl) ^ (row & 7);
        bfr[ni][kk] = *(const bf16x8*)&LB(buf)[row * 64 + pch * 8];
      }
    }
  };

#define BAR() __builtin_amdgcn_s_barrier()
#define LGKM0() asm volatile("s_waitcnt lgkmcnt(0)" ::: "memory")
#define MFMA_Q(q)                                                        \
  do {                                                                   \
    __builtin_amdgcn_s_setprio(1);                                       \
    _Pragma("unroll")                                                    \
    for (int f = 0; f < 2; ++f)                                          \
      _Pragma("unroll")                                                  \
      for (int ni = 0; ni < 4; ++ni)                                     \
        _Pragma("unroll")                                                \
        for (int kk = 0; kk < 2; ++kk)                                   \
          acc[(q) * 2 + f][ni] = __builtin_amdgcn_mfma_f32_16x16x32_bf16(\
              af[f][kk], bfr[ni][kk], acc[(q) * 2 + f][ni], 0, 0, 0);    \
    __builtin_amdgcn_s_setprio(0);                                       \
  } while (0)

  // prologue: tile0 (buf0) fully + tile1 B-halves (buf1) = 12 loads/thread
  stageB(0, 0, 0); stageB(0, 0, 1);
  stageA(0, 0, 0); stageA(0, 0, 1);
  stageB(1, 1, 0); stageB(1, 1, 1);
  asm volatile("s_waitcnt vmcnt(4)" ::: "memory");   // tile0 landed
  BAR();

  for (int t2 = 0; t2 < NKT; t2 += 2) {
    const bool more = (t2 + 4 <= NKT);   // tiles t2+2 / t2+3 exist
    // ---- K-tile t2 (buf0) ----
    loadB(0); loadA(0, 0);
    stageA(1, t2 + 1, 0); stageA(1, t2 + 1, 1);
    BAR(); LGKM0(); MFMA_Q(0); BAR();
    loadA(0, 1);
    if (more) stageB(0, t2 + 2, 0);
    BAR(); LGKM0(); MFMA_Q(1); BAR();
    loadA(0, 2);
    if (more) stageB(0, t2 + 2, 1);
    BAR(); LGKM0(); MFMA_Q(2); BAR();
    loadA(0, 3);
    if (more) { asm volatile("s_waitcnt vmcnt(4)" ::: "memory"); }
    else      { asm volatile("s_waitcnt vmcnt(0)" ::: "memory"); }
    BAR(); LGKM0(); MFMA_Q(3); BAR();
    // ---- K-tile t2+1 (buf1) ----
    loadB(1); loadA(1, 0);
    if (more) stageA(0, t2 + 2, 0);
    BAR(); LGKM0(); MFMA_Q(0); BAR();
    loadA(1, 1);
    if (more) stageA(0, t2 + 2, 1);
    BAR(); LGKM0(); MFMA_Q(1); BAR();
    loadA(1, 2);
    if (more) stageB(1, t2 + 3, 0);
    BAR(); LGKM0(); MFMA_Q(2); BAR();
    loadA(1, 3);
    if (more) stageB(1, t2 + 3, 1);
    if (more) { asm volatile("s_waitcnt vmcnt(4)" ::: "memory"); }
    else      { asm volatile("s_waitcnt vmcnt(0)" ::: "memory"); }
    BAR(); LGKM0(); MFMA_Q(3); BAR();
  }
#undef BAR
#undef LGKM0
#undef MFMA_Q

  // ---- epilogue: D lane map col=lane&15, row=(lane>>4)*4+r (m89/m91) ----
  if constexpr (EPI == 2) {
    // energy: direct stores (r11 form; measured faster than LDS staging)
    if (tid < 256) rsum_l[tid] = 0.f;
    __syncthreads();
#pragma unroll
    for (int mi = 0; mi < 8; ++mi) {
      int lrow0 = wr * 128 + (mi >> 1) * 32 + (mi & 1) * 16 + (cl << 2);
#pragma unroll
      for (int r = 0; r < 4; ++r) {
        float part = 0.f;
#pragma unroll
        for (int ni = 0; ni < 4; ++ni) {
          long col = bn + wc * 64 + ni * 16 + rr;
          float e = __expf(acc[mi][ni][r] * scale);
          C[(long)bz * cbatch + (bm + lrow0 + r) * ldc + col] = f2bf(e);
          part += e;
        }
        part += __shfl_xor(part, 1);
        part += __shfl_xor(part, 2);
        part += __shfl_xor(part, 4);
        part += __shfl_xor(part, 8);
        if (rr == 0) atomicAdd(&rsum_l[lrow0 + r], part);
      }
    }
    __syncthreads();
    if (tid < 256) atomicAdd(&rs[(long)bz * 4096 + bm + tid], rsum_l[tid]);
  } else {
    // EPI 0/1: stage result in dead operand LDS, then coalesced short8 stores
    short* cstage = &lsmem[0][0];
    auto stc = [&](int row, int col, short v) {
      int g = (col >> 3) ^ ((row >> 2) & 7);
      cstage[row * 256 + g * 8 + (col & 7)] = v;
    };
    if constexpr (EPI == 1) {
#pragma unroll
      for (int mi = 0; mi < 8; ++mi) {
        int lrow0 = wr * 128 + (mi >> 1) * 32 + (mi & 1) * 16 + (cl << 2);
        float inv[4];
#pragma unroll
        for (int r = 0; r < 4; ++r)
          inv[r] = 1.f / rs[(long)bz * 4096 + bm + lrow0 + r];
#pragma unroll
        for (int ni = 0; ni < 4; ++ni) {
          int col = wc * 64 + ni * 16 + rr;
#pragma unroll
          for (int r = 0; r < 4; ++r)
            stc(lrow0 + r, col, f2bf(acc[mi][ni][r] * scale * inv[r]));
        }
      }
    } else {
#pragma unroll
      for (int mi = 0; mi < 8; ++mi) {
        int lrow0 = wr * 128 + (mi >> 1) * 32 + (mi & 1) * 16 + (cl << 2);
#pragma unroll
        for (int ni = 0; ni < 4; ++ni) {
          int col = wc * 64 + ni * 16 + rr;
#pragma unroll
          for (int r = 0; r < 4; ++r)
            stc(lrow0 + r, col, f2bf(acc[mi][ni][r] * scale));
        }
      }
    }
    __syncthreads();
    // coalesced store: 16 x short8 per thread (skip-add fused for EPI=1)
#pragma unroll
    for (int it = 0; it < 16; ++it) {
      int g = it * 512 + tid;            // granule id 0..8191
      int row = g >> 5, cg = g & 31;
      int gphys = cg ^ ((row >> 2) & 7);
      short8 v8 = *(short8*)&cstage[row * 256 + gphys * 8];
      if constexpr (EPI == 1) {
        const short8 a8 = *(const short8*)&addp[
            (long)bz * addbatch + (bm + row) * (long)ldadd + bn + cg * 8];
#pragma unroll
        for (int j = 0; j < 8; ++j) v8[j] = f2bf(bf2f(v8[j]) + bf2f(a8[j]));
      }
      *(short8*)&C[(long)bz * cbatch + (bm + row) * (long)ldc + bn + cg * 8] = v8;
    }
  }
#undef LA
#undef LB
}

// ---------------------------------------------------------------------------
// 2-phase 128-tile BT GEMM (round-4 proven) for the small c1/c2 GEMMs.
// ---------------------------------------------------------------------------
__device__ __forceinline__ int swz32(int row, int ch) {
  return row * 32 + ((ch ^ ((row >> 1) & 3)) << 3);
}

template <int BM, int BN, int WR, int WC, int EPI>
__global__ __launch_bounds__(WR * WC * 64, 4) void gemm_bt(
    const short* __restrict__ A, const short* __restrict__ B,
    short* __restrict__ C, const short* __restrict__ addp,
    const float* __restrict__ sc, const float* __restrict__ sh,
    int K, int lda, int ldb, int ldc,
    long abatch, long bbatch, long cbatch, float scale)
{
  constexpr int NTH = WR * WC * 64;
  constexpr int WM = BM / WR, WN = BN / WC;
  constexpr int MR = WM / 16, NR = WN / 16;
  constexpr int CA = (BM * 4) / NTH, CB = (BN * 4) / NTH;

  __shared__ __align__(16) short lA[2][BM * 32];
  __shared__ __align__(16) short lB[2][BN * 32];

  int bx = blockIdx.x, by = blockIdx.y, bz = blockIdx.z;
  xcd_map(bx, by, bz);

  const int tid = threadIdx.x;
  const int lane = tid & 63, wid = tid >> 6;
  const int wr = wid / WC, wc = wid % WC;

  const long bm = (long)bx * BM, bn = (long)by * BN;
  const short* Ab = A + (long)bz * abatch + bm * lda;
  const short* Bb = B + (long)bz * bbatch + bn * ldb;

  f32x4 acc[MR][NR] = {};

  auto stage = [&](int buf, int k0) {
#pragma unroll
    for (int i = 0; i < CA; ++i) {
      int idx = i * NTH + tid, row = idx >> 2, ch = idx & 3;
      int chs = ch ^ ((row >> 1) & 3);
      __builtin_amdgcn_global_load_lds(
          (const AS1 void*)(Ab + (long)row * lda + k0 + chs * 8),
          (AS3 void*)(&lA[buf][idx * 8]), 16, 0, 0);
    }
#pragma unroll
    for (int i = 0; i < CB; ++i) {
      int idx = i * NTH + tid, row = idx >> 2, ch = idx & 3;
      int chs = ch ^ ((row >> 1) & 3);
      __builtin_amdgcn_global_load_lds(
          (const AS1 void*)(Bb + (long)row * ldb + k0 + chs * 8),
          (AS3 void*)(&lB[buf][idx * 8]), 16, 0, 0);
    }
  };

  const int NT = K >> 5;
  stage(0, 0);
  __syncthreads();
  int cur = 0;
  for (int t = 0; t < NT; ++t) {
    if (t + 1 < NT) stage(cur ^ 1, (t + 1) << 5);
    const int ch = lane >> 4, rrow = lane & 15;
    bf16x8 af[MR], bfr[NR];
#pragma unroll
    for (int mi = 0; mi < MR; ++mi) {
      int row = wr * WM + mi * 16 + rrow;
      af[mi] = *(const bf16x8*)&lA[cur][swz32(row, ch)];
    }
#pragma unroll
    for (int ni = 0; ni < NR; ++ni) {
      int row = wc * WN + ni * 16 + rrow;
      bfr[ni] = *(const bf16x8*)&lB[cur][swz32(row, ch)];
    }
    __builtin_amdgcn_s_setprio(1);
#pragma unroll
    for (int mi = 0; mi < MR; ++mi)
#pragma unroll
      for (int ni = 0; ni < NR; ++ni)
        acc[mi][ni] = __builtin_amdgcn_mfma_f32_16x16x32_bf16(
            af[mi], bfr[ni], acc[mi][ni], 0, 0, 0);
    __builtin_amdgcn_s_setprio(0);
    __syncthreads();
    cur ^= 1;
  }

#pragma unroll
  for (int mi = 0; mi < MR; ++mi) {
    long row0 = bm + wr * WM + mi * 16 + ((lane >> 4) << 2);
#pragma unroll
    for (int ni = 0; ni < NR; ++ni) {
      long col = bn + wc * WN + ni * 16 + (lane & 15);
#pragma unroll
      for (int r = 0; r < 4; ++r) {
        long off = (long)bz * cbatch + (row0 + r) * ldc + col;
        float v = acc[mi][ni][r] * scale;
        if constexpr (EPI == 1) v += bf2f(addp[off]);
        if constexpr (EPI == 2) {
          float y = v * sc[col] + sh[col];
          v = y / (1.f + __expf(-y));
        }
        C[off] = f2bf(v);
      }
    }
  }
}

// ---------------------------------------------------------------------------
__global__ __launch_bounds__(256) void transpose_cvt(
    const float* __restrict__ in, short* __restrict__ out, int C, int N)
{
  __shared__ float tile[32][33];
  int n0 = blockIdx.x * 32, c0 = blockIdx.y * 32;
  long z = (long)blockIdx.z * C * N;
  int tx = threadIdx.x & 31, ty = threadIdx.x >> 5;
#pragma unroll
  for (int r = 0; r < 4; ++r) {
    int cc = ty + r * 8;
    tile[cc][tx] = in[z + (long)(c0 + cc) * N + n0 + tx];
  }
  __syncthreads();
#pragma unroll
  for (int r = 0; r < 4; ++r) {
    int nn = ty + r * 8;
    out[z + (long)(n0 + nn) * C + c0 + tx] = f2bf(tile[tx][nn]);
  }
}

__global__ __launch_bounds__(256) void cvt_bf16(
    const float* __restrict__ in, short* __restrict__ out, long n)
{
  long i = ((long)blockIdx.x * 256 + threadIdx.x) * 4;
  if (i >= n) return;
  const float* p = in + i;
  short4v s;
  s[0] = f2bf(p[0]); s[1] = f2bf(p[1]); s[2] = f2bf(p[2]); s[3] = f2bf(p[3]);
  *(short4v*)(out + i) = s;
}

__global__ void bn_prep(const float* g1, const float* b1, const float* m1, const float* v1,
                        const float* g2, const float* b2, const float* m2, const float* v2,
                        float* s1, float* t1, float* s2, float* t2)
{
  int i = threadIdx.x;
  if (i < 256) { float s = g1[i] * rsqrtf(v1[i] + 1e-5f); s1[i] = s; t1[i] = b1[i] - m1[i] * s; }
  if (i < 64)  { float s = g2[i] * rsqrtf(v2[i] + 1e-5f); s2[i] = s; t2[i] = b2[i] - m2[i] * s; }
}

__global__ __launch_bounds__(256) void zerof(float* __restrict__ p, int n)
{
  int i = blockIdx.x * 256 + threadIdx.x;
  if (i < n) p[i] = 0.f;
}

__global__ __launch_bounds__(256) void c3_out(
    const short* __restrict__ y2, const float* __restrict__ w,
    const float* __restrict__ bias, float* __restrict__ o, int total)
{
  int i = blockIdx.x * 256 + threadIdx.x;
  if (i >= total) return;
  const short8* r = (const short8*)(y2 + (long)i * 64);
  float acc = 0.f;
#pragma unroll
  for (int j0 = 0; j0 < 8; ++j0) {
    short8 v = r[j0];
#pragma unroll
    for (int j = 0; j < 8; ++j) acc += bf2f(v[j]) * w[j0 * 8 + j];
  }
  acc += bias[0];
  float x = acc * LOG20F;
  o[i] = 1.f / (1.f + __expf(-x));
}

// ---------------------------------------------------------------------------
extern "C" void kernel_launch(void* const* d_in, const int* in_sizes, int n_in,
                              void* d_out, int out_size, void* d_ws, size_t ws_size,
                              hipStream_t stream) {
  const float* pcd  = (const float*)d_in[0];
  const float* img  = (const float*)d_in[1];
  const float* qw   = (const float*)d_in[2];
  const float* kw   = (const float*)d_in[3];
  const float* vw   = (const float*)d_in[4];
  const float* skw  = (const float*)d_in[5];
  const float* c1w  = (const float*)d_in[6];
  const float* bn1g = (const float*)d_in[7];
  const float* bn1b = (const float*)d_in[8];
  const float* bn1m = (const float*)d_in[9];
  const float* bn1v = (const float*)d_in[10];
  const float* c2w  = (const float*)d_in[11];
  const float* bn2g = (const float*)d_in[12];
  const float* bn2b = (const float*)d_in[13];
  const float* bn2m = (const float*)d_in[14];
  const float* bn2v = (const float*)d_in[15];
  const float* c3w  = (const float*)d_in[16];
  const float* c3b  = (const float*)d_in[17];
  float* out = (float*)d_out;

  char* ws = (char*)d_ws;
  const long QS  = 4096L * 1024;   // (4096,1024) elems
  const long QS2 = 4096L * 2048;   // fused q|skip
  const long ES  = 4096L * 4096;
  const size_t ALGN = 256;
  auto align_up = [&](size_t x) { return (x + ALGN - 1) & ~(ALGN - 1); };

  size_t oPcd  = 0;
  size_t oImg  = align_up(oPcd + 8L * 4096 * 1152 * 2);
  size_t oQsk  = align_up(oImg + 8L * 4096 * 1024 * 2);
  size_t oKt   = align_up(oQsk + 8L * QS2 * 2);
  size_t oV    = align_up(oKt  + 8L * QS * 2);
  size_t oWqs  = align_up(oV   + 8L * QS * 2);
  size_t oWk   = align_up(oWqs + 2048L * 1152 * 2);
  size_t oWv   = align_up(oWk + 1024L * 1024 * 2);
  size_t oC1   = align_up(oWv + 1024L * 1024 * 2);
  size_t oC2   = align_up(oC1 + 256L * 1024 * 2);
  size_t oS1   = align_up(oC2 + 64L * 256 * 2);
  size_t oT1   = align_up(oS1 + 256 * 4);
  size_t oS2   = align_up(oT1 + 256 * 4);
  size_t oT2   = align_up(oS2 + 64 * 4);
  size_t oRs   = align_up(oT2 + 64 * 4);
  size_t oEnd  = align_up(oRs + 8L * 4096 * 4);

  short* pcdT  = (short*)(ws + oPcd);
  short* imgT  = (short*)(ws + oImg);
  short* qsk   = (short*)(ws + oQsk);   // [b][4096][2048]: q 0-1023, skip 1024+
  short* kt    = (short*)(ws + oKt);
  short* vbuf  = (short*)(ws + oV);
  short* wqsk  = (short*)(ws + oWqs);   // [2048][1152]: Wq rows then Wskip rows
  short* wkb   = (short*)(ws + oWk);
  short* wvb   = (short*)(ws + oWv);
  short* c1b   = (short*)(ws + oC1);
  short* c2b   = (short*)(ws + oC2);
  float* s1 = (float*)(ws + oS1); float* t1 = (float*)(ws + oT1);
  float* s2 = (float*)(ws + oS2); float* t2 = (float*)(ws + oT2);
  float* rsum = (float*)(ws + oRs);

  // attn/xt: NB=8 -> fresh 256MB attn + 64MB xt after oEnd; NB=4 -> attn
  // aliases region A [pcdT|imgT] (128 <= 142.6 MB), xt fresh; NB=2 ->
  // attn + xt both inside region A.
  int NB; short *attn, *xt;
  if (ws_size >= oEnd + (size_t)(8L * ES * 2) + (size_t)(8L * QS * 2)) {
    NB = 8; attn = (short*)(ws + oEnd);
    xt = (short*)(ws + align_up(oEnd + (size_t)(8L * ES * 2)));
  } else if (ws_size >= oEnd + (size_t)(8L * QS * 2)) {
    NB = 4; attn = (short*)(ws + 0); xt = (short*)(ws + oEnd);
  } else {
    NB = 2; attn = (short*)(ws + 0);
    xt = (short*)(ws + align_up((size_t)(2L * ES * 2)));
  }
  short* y1t = qsk;   // qsk dead after attention loop
  short* y2t = kt;    // kt dead after attention loop

  // weight converts + bn prep
  cvt_bf16<<<dim3(1152), 256, 0, stream>>>(qw,  wqsk,                1024L * 1152);
  cvt_bf16<<<dim3(1152), 256, 0, stream>>>(skw, wqsk + 1024L * 1152, 1024L * 1152);
  cvt_bf16<<<dim3(1024), 256, 0, stream>>>(kw,  wkb,  1024L * 1024);
  cvt_bf16<<<dim3(1024), 256, 0, stream>>>(vw,  wvb,  1024L * 1024);
  cvt_bf16<<<dim3(256),  256, 0, stream>>>(c1w, c1b,  256L * 1024);
  cvt_bf16<<<dim3(16),   256, 0, stream>>>(c2w, c2b,  64L * 256);
  bn_prep<<<1, 256, 0, stream>>>(bn1g, bn1b, bn1m, bn1v, bn2g, bn2b, bn2m, bn2v,
                                 s1, t1, s2, t2);
  zerof<<<dim3(128), 256, 0, stream>>>(rsum, 8 * 4096);
  transpose_cvt<<<dim3(128, 36, 8), 256, 0, stream>>>(pcd, pcdT, 1152, 4096);
  transpose_cvt<<<dim3(128, 32, 8), 256, 0, stream>>>(img, imgT, 1024, 4096);

  // fused q+skip projection: qsk[n, 0:2048], K=1152 (NKT=18)
  gemm8<0><<<dim3(16, 8, 8), 512, 0, stream>>>(
      pcdT, wqsk, qsk, nullptr, nullptr,
      1152, 1152, 1152, 2048, 0, 4096L * 1152, 0, QS2, 0, 1.f);
  // kt projection
  gemm8<0><<<dim3(16, 4, 8), 512, 0, stream>>>(
      imgT, wkb, kt, nullptr, nullptr,
      1024, 1024, 1024, 1024, 0, QS, 0, QS, 0, 1.f);
  // v projection (transposed output): v[o, m]
  gemm8<0><<<dim3(4, 16, 8), 512, 0, stream>>>(
      wvb, imgT, vbuf, nullptr, nullptr,
      1024, 1024, 1024, 4096, 0, 0, QS, QS, 0, 1.f);

  // attention (softmax folded into GEMM epilogues via rsum)
  for (int b0 = 0; b0 < 8; b0 += NB) {
    // e[n,m] = exp(E[n,m]/32); rsum[n] += row sums
    gemm8<2><<<dim3(16, 16, NB), 512, 0, stream>>>(
        qsk + (long)b0 * QS2, kt + (long)b0 * QS, attn, nullptr,
        rsum + (long)b0 * 4096,
        1024, 2048, 1024, 4096, 0, QS2, QS, ES, 0, 0.03125f);
    // xt[n,c] = (sum_m e[n,m] v[c,m]) / rsum[n] + skip[n,c]
    gemm8<1><<<dim3(16, 4, NB), 512, 0, stream>>>(
        attn, vbuf + (long)b0 * QS, xt + (long)b0 * QS,
        qsk + (long)b0 * QS2 + 1024, rsum + (long)b0 * 4096,
        4096, 4096, 4096, 1024, 2048, ES, QS, QS, QS2, 1.f);
  }

  // c1/c2: proven 2-phase 128-tile path
  gemm_bt<128, 128, 2, 2, 2><<<dim3(32, 2, 8), 256, 0, stream>>>(
      xt, c1b, y1t, nullptr, s1, t1,
      1024, 1024, 1024, 256, QS, 0, 4096L * 256, 1.f);
  gemm_bt<128, 64, 4, 1, 2><<<dim3(32, 1, 8), 256, 0, stream>>>(
      y1t, c2b, y2t, nullptr, s2, t2,
      256, 256, 256, 64, 4096L * 256, 0, 4096L * 64, 1.f);
  c3_out<<<dim3(128), 256, 0, stream>>>(y2t, c3w, c3b, out, 32768);

  (void)in_sizes; (void)n_in; (void)out_size; (void)ws_size;
}